// Round 12
// baseline (730.584 us; speedup 1.0000x reference)
//
#include <hip/hip_runtime.h>
#include <hip/hip_bf16.h>
#include <math.h>

// Problem constants (B=4, S=2048, D=768, H=3072, E=8, K=2, cap_factor=1.5)
#define TOK    8192          // B*S tokens
#define DMODEL 768
#define HDIM   3072
#define NEXP   8
#define CAP    1536          // int((B*S/E)*1.5)
#define NFLAT  (TOK*2)

typedef __attribute__((ext_vector_type(8))) short bf16x8;
typedef __attribute__((ext_vector_type(4))) float f32x4;

static __device__ __forceinline__ unsigned short f2bf(float f) {
  unsigned int u = __float_as_uint(f);
  u += 0x7FFF + ((u >> 16) & 1);          // round-to-nearest-even
  return (unsigned short)(u >> 16);
}

// fast gelu: v*sigmoid(2y), y = 0.79788456*(v + 0.044715 v^3); ~8 VALU vs ~22 for erff.
static __device__ __forceinline__ float fast_gelu(float v) {
  const float v2 = v * v;
  const float y2 = v * (1.59576912f + 0.07135534f * v2);   // 2*y
  const float e  = __expf(y2);
  return v - v * __builtin_amdgcn_rcpf(e + 1.0f);
}

// ---------------- 1. Router: fp64 logits, top-2, renormalized weights ----------------
__global__ __launch_bounds__(256)
void moe_router(const float* __restrict__ x, const float* __restrict__ Wr,
                int* __restrict__ eidx, float* __restrict__ pw)
{
  const int wid = threadIdx.x >> 6, lane = threadIdx.x & 63;
  const int t = blockIdx.x * 4 + wid;
  const float* xr = x + (size_t)t * DMODEL;
  double acc[NEXP];
#pragma unroll
  for (int e = 0; e < NEXP; ++e) acc[e] = 0.0;
  for (int j = 0; j < DMODEL / 64; ++j) {
    const int d = j * 64 + lane;
    const double xv = (double)xr[d];
    const float* wrow = Wr + (size_t)d * NEXP;
#pragma unroll
    for (int e = 0; e < NEXP; ++e) acc[e] += xv * (double)wrow[e];
  }
#pragma unroll
  for (int off = 32; off > 0; off >>= 1) {
#pragma unroll
    for (int e = 0; e < NEXP; ++e) acc[e] += __shfl_xor(acc[e], off, 64);
  }
  if (lane == 0) {
    int e0 = 0;
    for (int e = 1; e < NEXP; ++e) if (acc[e] > acc[e0]) e0 = e;
    int e1 = (e0 == 0) ? 1 : 0;
    for (int e = 0; e < NEXP; ++e) { if (e == e0) continue; if (acc[e] > acc[e1]) e1 = e; }
    const double p0 = 1.0 / (1.0 + exp(acc[e1] - acc[e0]));
    eidx[t * 2 + 0] = e0; eidx[t * 2 + 1] = e1;
    pw[t * 2 + 0] = (float)p0; pw[t * 2 + 1] = (float)(1.0 - p0);
  }
}

// ---------------- 2. Capacity assignment (int4-vectorized reads) ----------------
__global__ __launch_bounds__(256)
void moe_assign(const int* __restrict__ eidx, int* __restrict__ slotpos,
                int* __restrict__ elist, int* __restrict__ counts)
{
  const int e = blockIdx.x;
  const int tid = threadIdx.x;
  const int base = tid * 64;
  const int4* p4 = (const int4*)(eidx + base);
  int cnt = 0;
#pragma unroll
  for (int j = 0; j < 16; ++j) {
    int4 v = p4[j];
    cnt += (v.x == e) + (v.y == e) + (v.z == e) + (v.w == e);
  }
  const int lane = tid & 63, wid = tid >> 6;
  int incl = cnt;
  for (int off = 1; off < 64; off <<= 1) {
    int u = __shfl_up(incl, off, 64);
    if (lane >= off) incl += u;
  }
  __shared__ int wsum[4];
  if (lane == 63) wsum[wid] = incl;
  __syncthreads();
  int wbase = 0;
  for (int w = 0; w < wid; ++w) wbase += wsum[w];
  int run = wbase + incl - cnt;
#pragma unroll
  for (int j = 0; j < 16; ++j) {
    int4 v = p4[j];
    const int n = base + j * 4;
    int vv[4] = {v.x, v.y, v.z, v.w};
#pragma unroll
    for (int q = 0; q < 4; ++q) {
      if (vv[q] == e) {
        const int pos = run++;
        slotpos[n + q] = (pos < CAP) ? pos : -1;
        if (pos < CAP) elist[e * CAP + pos] = (n + q) >> 1;
      }
    }
  }
  if (tid == 255) {
    int tot = wbase + incl;
    counts[e] = (tot < CAP) ? tot : CAP;
  }
}

// ---------------- 3. Transpose + fp32->bf16 (vectorized: float4 in, ushort4 out) --------
// in: [E][R][C] f32 -> out: [E][C][R] bf16. grid (C/64, R/64, E), 256 thr.
__global__ __launch_bounds__(256)
void transpose_bf16(const float* __restrict__ in, unsigned short* __restrict__ out,
                    int R, int C)
{
  __shared__ unsigned short tile[64][65];   // [r][c], pad 1 (2-way banks = free)
  const int e = blockIdx.z;
  in  += (size_t)e * R * C;
  out += (size_t)e * C * R;
  const int c0 = blockIdx.x * 64, r0 = blockIdx.y * 64;
  const int tid = threadIdx.x;
  const int rL = tid >> 4;                  // 0..15
  const int cq = (tid & 15) * 4;            // col quad
#pragma unroll
  for (int p = 0; p < 4; ++p) {
    const int r = rL + p * 16;
    float4 v = *(const float4*)&in[(size_t)(r0 + r) * C + c0 + cq];
    tile[r][cq + 0] = f2bf(v.x);
    tile[r][cq + 1] = f2bf(v.y);
    tile[r][cq + 2] = f2bf(v.z);
    tile[r][cq + 3] = f2bf(v.w);
  }
  __syncthreads();
  const int cL = tid >> 4;                  // 0..15
  const int rq = (tid & 15) * 4;            // row quad (consecutive lanes -> coalesced)
#pragma unroll
  for (int p = 0; p < 4; ++p) {
    const int cc = cL + p * 16;
    ushort4 o;
    o.x = tile[rq + 0][cc]; o.y = tile[rq + 1][cc];
    o.z = tile[rq + 2][cc]; o.w = tile[rq + 3][cc];
    *(ushort4*)&out[(size_t)(c0 + cc) * R + r0 + rq] = o;
  }
}

// ---------------- 4. Gather tokens per expert into contiguous bf16 rows ----------------
__global__ __launch_bounds__(64)
void moe_gather(const float* __restrict__ x, const int* __restrict__ elist,
                const int* __restrict__ counts, unsigned short* __restrict__ Xg)
{
  const int p = blockIdx.x, e = blockIdx.y;
  const int lane = threadIdx.x;
  unsigned short* dst = Xg + ((size_t)e * CAP + p) * DMODEL;
  if (p >= counts[e]) {
    ushort4 z; z.x = z.y = z.z = z.w = 0;
#pragma unroll
    for (int j = 0; j < 3; ++j) ((ushort4*)dst)[j * 64 + lane] = z;
    return;
  }
  const int tok = elist[e * CAP + p];
  const float4* src = (const float4*)(x + (size_t)tok * DMODEL);
#pragma unroll
  for (int j = 0; j < 3; ++j) {
    float4 v = src[j * 64 + lane];
    ushort4 o;
    o.x = f2bf(v.x); o.y = f2bf(v.y); o.z = f2bf(v.z); o.w = f2bf(v.w);
    ((ushort4*)dst)[j * 64 + lane] = o;
  }
}

// ---------------- 5. Grouped GEMM: reg-staged, XOR-swizzled row-major LDS ----------------
// (r10/r11-verified structure: VGPR 76 @MI=4, no spill, clean counters.)
// BM = MI*32 x 128 tile, 256 thr = 4 waves (2x2), wave out (MI*16) x 64,
// acc[MI][4] (-> AGPRs). Bare __launch_bounds__(256): a min-waves floor makes
// the allocator cap arch VGPRs at 64 and spill staging regs (r9: 588MB scratch).
// Transport: global_load_dwordx4 -> regs -> ds_write_b128; loads for tile t+1
// issue BEFORE compute(t). LDS [BM][64] ush, 16B-chunk XOR swizzle both sides.
// MI=8 (GEMM1): 64 MFMA per wave-K-step per 12 staging instrs (2x the MFMA
// density of MI=4) -- attacks the 31.6% MfmaUtil issue-rate limit.
// ORD=0: mt fastest (GEMM1); ORD=1: nt fastest (GEMM2, r11-verified fetch fix).
// EPI=0: bf16(fast_gelu(acc+bias)) via LDS-staged coalesced stores, BM/128
//        row-halves per pass. EPI=1: direct f32; ks picks Cout0/1.
template <int EPI, int ORD, int MI>
__global__ __launch_bounds__(256)
void moe_rs(const unsigned short* __restrict__ Ag, int lda,
            const unsigned short* __restrict__ Bg, int ldb,
            void* __restrict__ Cout0, void* __restrict__ Cout1, int ldc,
            const float* __restrict__ bias,
            int Nsize, int NT, int MT, int NTN)
{
  constexpr int BM  = MI * 32;
  constexpr int ASZ = BM * 64;              // ush elements of A region
  __shared__ __align__(16) unsigned short lds[ASZ + 8192];
  unsigned short* const ldsA = lds;
  unsigned short* const ldsB = lds + ASZ;

  // XCD swizzle: per-XCD contiguous chunk = one expert's tiles
  const int cpx = gridDim.x >> 3;
  const int swz = (blockIdx.x & 7) * cpx + (blockIdx.x >> 3);
  const int e  = swz / cpx;
  int rd = swz - e * cpx;
  int mt, nt, ks;
  if (ORD == 0) { mt = rd % MT;  rd /= MT;  nt = rd % NTN; ks = rd / NTN; }
  else          { nt = rd % NTN; rd /= NTN; mt = rd % MT;  ks = rd / MT;  }
  const int m0 = mt * BM, n0 = nt * 128;
  const int kb = ks * NT * 64;

  const unsigned short* Ae = Ag + (size_t)e * CAP * lda;
  const unsigned short* Be = Bg + (size_t)e * Nsize * ldb;

  const int tid = threadIdx.x, lane = tid & 63, wid = tid >> 6;
  const int wr = wid >> 1, wc = wid & 1;
  const int r16 = lane & 15, g4 = lane >> 4;

  // staging: rows srow+32j (j<MI for A, j<4 for B), 16B chunk scol; global
  // row-contiguous (8 lanes x 16B = 128B/row), LDS dest chunk XOR-swizzled.
  const int srow  = tid >> 3;                 // 0..31
  const int scol  = tid & 7;                  // 0..7
  const int scolX = scol ^ (srow & 7);        // (srow+32k)&7 == srow&7
  const unsigned short* pA = Ae + (size_t)(m0 + srow) * lda + scol * 8 + kb;
  const unsigned short* pB = Be + (size_t)(n0 + srow) * ldb + scol * 8 + kb;
  unsigned short* qA = &ldsA[srow * 64 + scolX * 8];
  unsigned short* qB = &ldsB[srow * 64 + scolX * 8];

  float4 a[MI], b[4];
  auto LOADT = [&](int tt) {
    const size_t ko = (size_t)tt * 64;
#pragma unroll
    for (int j = 0; j < MI; ++j) a[j] = *(const float4*)(pA + ko + (size_t)(32 * j) * lda);
#pragma unroll
    for (int j = 0; j < 4; ++j)  b[j] = *(const float4*)(pB + ko + (size_t)(32 * j) * ldb);
  };
  auto STORET = [&]() {
#pragma unroll
    for (int j = 0; j < MI; ++j) *(float4*)(qA + j * 2048) = a[j];
#pragma unroll
    for (int j = 0; j < 4; ++j)  *(float4*)(qB + j * 2048) = b[j];
  };

  f32x4 acc[MI][4];
#pragma unroll
  for (int i = 0; i < MI; ++i)
#pragma unroll
    for (int j = 0; j < 4; ++j) acc[i][j] = (f32x4){0.f, 0.f, 0.f, 0.f};

  // per-thread read offsets (swizzled): chunk = (kh*4+g4) ^ (row&7)
  const int cx0 = (g4 ^ (r16 & 7)) * 8;
  const int rA = (wr * (MI * 16) + r16) * 64;   // + mi*16*64
  const int rB = (wc * 64 + r16) * 64;

  LOADT(0);
  for (int t = 0; t < NT; ++t) {
    __syncthreads();                 // all waves done reading LDS(t-1)
    STORET();                        // compiler inserts vmcnt wait here
    if (t + 1 < NT) LOADT(t + 1);    // in flight during compute(t)
    __syncthreads();                 // LDS(t) visible
#pragma unroll
    for (int kh = 0; kh < 2; ++kh) {
      const int cx = cx0 ^ (kh * 32);
      bf16x8 aF[MI], bF[4];
#pragma unroll
      for (int mi = 0; mi < MI; ++mi)
        aF[mi] = *(const bf16x8*)&ldsA[rA + mi * 1024 + cx];
#pragma unroll
      for (int ni = 0; ni < 4; ++ni)
        bF[ni] = *(const bf16x8*)&ldsB[rB + ni * 1024 + cx];
#pragma unroll
      for (int mi = 0; mi < MI; ++mi)
#pragma unroll
        for (int ni = 0; ni < 4; ++ni)
          acc[mi][ni] = __builtin_amdgcn_mfma_f32_16x16x32_bf16(aF[mi], bF[ni], acc[mi][ni], 0, 0, 0);
    }
  }

  // ---- epilogue. C/D layout: col = lane&15, row = 4*(lane>>4)+reg ----
  const float* bvec = bias + (size_t)e * Nsize;
  if constexpr (EPI == 0) {
    // stage bf16 tile through LDS ([128][128] ush = 32KB) in BM/128 row-halves
    constexpr int NP = BM / 128;
#pragma unroll
    for (int p = 0; p < NP; ++p) {
      __syncthreads();
      if (NP == 1 || wr == p) {
#pragma unroll
        for (int ni = 0; ni < 4; ++ni) {
          const int lc = wc * 64 + ni * 16 + r16;
          const float bv = bvec[n0 + lc];
#pragma unroll
          for (int mi = 0; mi < MI; ++mi) {
            const int lr0 = (NP == 1 ? wr * 64 : 0) + mi * 16 + 4 * g4;
#pragma unroll
            for (int reg = 0; reg < 4; ++reg)
              lds[(lr0 + reg) * 128 + lc] = f2bf(fast_gelu(acc[mi][ni][reg] + bv));
          }
        }
      }
      __syncthreads();
      unsigned short* C = (unsigned short*)Cout0 + (size_t)e * CAP * ldc;
#pragma unroll
      for (int it = 0; it < 8; ++it) {             // 2048 chunks of 8 shorts
        const int chunk = it * 256 + tid;
        const int row = chunk >> 4, c8 = chunk & 15;
        *(float4*)(C + (size_t)(m0 + p * 128 + row) * ldc + n0 + c8 * 8) =
            *(const float4*)&lds[chunk * 8];
      }
    }
  } else {
    float* C = (float*)(ks ? Cout1 : Cout0) + (size_t)e * CAP * ldc;
#pragma unroll
    for (int ni = 0; ni < 4; ++ni) {
      const int gc = n0 + wc * 64 + ni * 16 + r16;
#pragma unroll
      for (int mi = 0; mi < MI; ++mi) {
        const int gr0 = m0 + wr * (MI * 16) + mi * 16 + 4 * g4;
#pragma unroll
        for (int reg = 0; reg < 4; ++reg)
          C[(size_t)(gr0 + reg) * ldc + gc] = acc[mi][ni][reg];
      }
    }
  }
}

// ---------------- 6. Combine: out[t] = sum over kept slots w*(Y0+Y1+b2[e]) ----------------
__global__ __launch_bounds__(192)
void moe_combine(const float* __restrict__ Y0, const float* __restrict__ Y1,
                 const float* __restrict__ b2, const int* __restrict__ eidx,
                 const float* __restrict__ pw, const int* __restrict__ slotpos,
                 float* __restrict__ out)
{
  const int t = blockIdx.x;
  const int tid = threadIdx.x;
  float4 acc; acc.x = acc.y = acc.z = acc.w = 0.f;
#pragma unroll
  for (int s = 0; s < 2; ++s) {
    const int pos = slotpos[t * 2 + s];
    if (pos >= 0) {
      const int e = eidx[t * 2 + s];
      const float w = pw[t * 2 + s];
      const size_t ro = ((size_t)e * CAP + pos) * DMODEL;
      float4 y0 = ((const float4*)(Y0 + ro))[tid];
      float4 y1 = ((const float4*)(Y1 + ro))[tid];
      float4 bv = ((const float4*)(b2 + (size_t)e * DMODEL))[tid];
      acc.x += w * (y0.x + y1.x + bv.x);
      acc.y += w * (y0.y + y1.y + bv.y);
      acc.z += w * (y0.z + y1.z + bv.z);
      acc.w += w * (y0.w + y1.w + bv.w);
    }
  }
  ((float4*)out)[(size_t)t * (DMODEL / 4) + tid] = acc;
}

// ---------------- launch ----------------
extern "C" void kernel_launch(void* const* d_in, const int* in_sizes, int n_in,
                              void* d_out, int out_size, void* d_ws, size_t ws_size,
                              hipStream_t stream)
{
  const float* x  = (const float*)d_in[0];
  const float* Wr = (const float*)d_in[1];
  const float* w1 = (const float*)d_in[2];
  const float* b1 = (const float*)d_in[3];
  const float* w2 = (const float*)d_in[4];
  const float* b2 = (const float*)d_in[5];
  float* out = (float*)d_out;

  char* ws = (char*)d_ws;
  const size_t SZ_W1T = (size_t)NEXP * HDIM * DMODEL * 2;   // 37.75 MB
  const size_t SZ_W2T = (size_t)NEXP * DMODEL * HDIM * 2;   // 37.75 MB
  const size_t SZ_XG  = (size_t)NEXP * CAP * DMODEL * 2;    // 18.87 MB
  const size_t SZ_H   = (size_t)NEXP * CAP * HDIM * 2;      // 75.50 MB
  const size_t SZ_Y   = (size_t)NEXP * CAP * DMODEL * 4;    // 37.75 MB
  unsigned short* w1t = (unsigned short*)(ws);               size_t off = SZ_W1T;
  unsigned short* w2t = (unsigned short*)(ws + off);         off += SZ_W2T;
  unsigned short* Xg  = (unsigned short*)(ws + off);         off += SZ_XG;
  unsigned short* Hb  = (unsigned short*)(ws + off);         off += SZ_H;
  float*          Y0  = (float*)(ws + off);                  off += SZ_Y;
  int*   eidx    = (int*)(ws + off);                         off += (size_t)TOK * 2 * 4;
  float* pw      = (float*)(ws + off);                       off += (size_t)TOK * 2 * 4;
  int*   slotpos = (int*)(ws + off);                         off += (size_t)NFLAT * 4;
  int*   elist   = (int*)(ws + off);                         off += (size_t)NEXP * CAP * 4;
  int*   counts  = (int*)(ws + off);
  float* Y1 = (float*)w1t;   // alias: w1t dead after GEMM1; sizes match exactly

  // 1. router (fp64 logits -> exact top-2 ordering)
  moe_router<<<TOK / 4, 256, 0, stream>>>(x, Wr, eidx, pw);
  // 2. capacity assignment
  moe_assign<<<NEXP, 256, 0, stream>>>(eidx, slotpos, elist, counts);
  // 3. weight transposes (n-major bf16, vectorized)
  transpose_bf16<<<dim3(HDIM / 64, DMODEL / 64, NEXP), 256, 0, stream>>>(w1, w1t, DMODEL, HDIM);
  transpose_bf16<<<dim3(DMODEL / 64, HDIM / 64, NEXP), 256, 0, stream>>>(w2, w2t, HDIM, DMODEL);
  // 4. gather per-expert token rows (bf16), zero pad rows
  moe_gather<<<dim3(CAP, NEXP), 64, 0, stream>>>(x, elist, counts, Xg);
  // 5. grouped GEMMs (reg-staged pipeline)
  //    GEMM1: [1536x3072x768]/expert, 256x128 tile (MI=8) -> 6*24*8 = 1152 blocks, NT=12
  moe_rs<0, 0, 8><<<1152, 256, 0, stream>>>(
      Xg, DMODEL, w1t, DMODEL, Hb, Hb, HDIM, b1, HDIM, /*NT=*/12, /*MT=*/6, /*NTN=*/24);
  //    GEMM2: [1536x768x3072]/expert, 128x128 (MI=4, control), K-split x2 -> 1152 blocks
  moe_rs<1, 1, 4><<<1152, 256, 0, stream>>>(
      Hb, HDIM, w2t, HDIM, Y0, Y1, DMODEL, b2, DMODEL, /*NT=*/24, /*MT=*/12, /*NTN=*/6);
  // 6. weighted combine (adds K-split partials + bias; deterministic)
  moe_combine<<<TOK, 192, 0, stream>>>(Y0, Y1, b2, eidx, pw, slotpos, out);
}

// Round 13
// 237.667 us; speedup vs baseline: 3.0740x; 3.0740x over previous
//
#include <hip/hip_runtime.h>
#include <hip/hip_bf16.h>
#include <math.h>

// Problem constants (B=4, S=2048, D=768, H=3072, E=8, K=2, cap_factor=1.5)
#define TOK    8192          // B*S tokens
#define DMODEL 768
#define HDIM   3072
#define NEXP   8
#define CAP    1536          // int((B*S/E)*1.5)
#define NFLAT  (TOK*2)

typedef __attribute__((ext_vector_type(8))) short bf16x8;
typedef __attribute__((ext_vector_type(4))) float f32x4;

static __device__ __forceinline__ unsigned short f2bf(float f) {
  unsigned int u = __float_as_uint(f);
  u += 0x7FFF + ((u >> 16) & 1);          // round-to-nearest-even
  return (unsigned short)(u >> 16);
}

// fast gelu: v*sigmoid(2y), y = 0.79788456*(v + 0.044715 v^3); ~8 VALU vs ~22 for erff.
static __device__ __forceinline__ float fast_gelu(float v) {
  const float v2 = v * v;
  const float y2 = v * (1.59576912f + 0.07135534f * v2);   // 2*y
  const float e  = __expf(y2);
  return v - v * __builtin_amdgcn_rcpf(e + 1.0f);
}

// ---------------- 1. Router: fp64 logits, top-2, renormalized weights ----------------
__global__ __launch_bounds__(256)
void moe_router(const float* __restrict__ x, const float* __restrict__ Wr,
                int* __restrict__ eidx, float* __restrict__ pw)
{
  const int wid = threadIdx.x >> 6, lane = threadIdx.x & 63;
  const int t = blockIdx.x * 4 + wid;
  const float* xr = x + (size_t)t * DMODEL;
  double acc[NEXP];
#pragma unroll
  for (int e = 0; e < NEXP; ++e) acc[e] = 0.0;
  for (int j = 0; j < DMODEL / 64; ++j) {
    const int d = j * 64 + lane;
    const double xv = (double)xr[d];
    const float* wrow = Wr + (size_t)d * NEXP;
#pragma unroll
    for (int e = 0; e < NEXP; ++e) acc[e] += xv * (double)wrow[e];
  }
#pragma unroll
  for (int off = 32; off > 0; off >>= 1) {
#pragma unroll
    for (int e = 0; e < NEXP; ++e) acc[e] += __shfl_xor(acc[e], off, 64);
  }
  if (lane == 0) {
    int e0 = 0;
    for (int e = 1; e < NEXP; ++e) if (acc[e] > acc[e0]) e0 = e;
    int e1 = (e0 == 0) ? 1 : 0;
    for (int e = 0; e < NEXP; ++e) { if (e == e0) continue; if (acc[e] > acc[e1]) e1 = e; }
    const double p0 = 1.0 / (1.0 + exp(acc[e1] - acc[e0]));
    eidx[t * 2 + 0] = e0; eidx[t * 2 + 1] = e1;
    pw[t * 2 + 0] = (float)p0; pw[t * 2 + 1] = (float)(1.0 - p0);
  }
}

// ---------------- 2. Capacity assignment (int4-vectorized reads) ----------------
__global__ __launch_bounds__(256)
void moe_assign(const int* __restrict__ eidx, int* __restrict__ slotpos,
                int* __restrict__ elist, int* __restrict__ counts)
{
  const int e = blockIdx.x;
  const int tid = threadIdx.x;
  const int base = tid * 64;
  const int4* p4 = (const int4*)(eidx + base);
  int cnt = 0;
#pragma unroll
  for (int j = 0; j < 16; ++j) {
    int4 v = p4[j];
    cnt += (v.x == e) + (v.y == e) + (v.z == e) + (v.w == e);
  }
  const int lane = tid & 63, wid = tid >> 6;
  int incl = cnt;
  for (int off = 1; off < 64; off <<= 1) {
    int u = __shfl_up(incl, off, 64);
    if (lane >= off) incl += u;
  }
  __shared__ int wsum[4];
  if (lane == 63) wsum[wid] = incl;
  __syncthreads();
  int wbase = 0;
  for (int w = 0; w < wid; ++w) wbase += wsum[w];
  int run = wbase + incl - cnt;
#pragma unroll
  for (int j = 0; j < 16; ++j) {
    int4 v = p4[j];
    const int n = base + j * 4;
    int vv[4] = {v.x, v.y, v.z, v.w};
#pragma unroll
    for (int q = 0; q < 4; ++q) {
      if (vv[q] == e) {
        const int pos = run++;
        slotpos[n + q] = (pos < CAP) ? pos : -1;
        if (pos < CAP) elist[e * CAP + pos] = (n + q) >> 1;
      }
    }
  }
  if (tid == 255) {
    int tot = wbase + incl;
    counts[e] = (tot < CAP) ? tot : CAP;
  }
}

// ---------------- 3. Transpose + fp32->bf16 (vectorized: float4 in, ushort4 out) --------
__global__ __launch_bounds__(256)
void transpose_bf16(const float* __restrict__ in, unsigned short* __restrict__ out,
                    int R, int C)
{
  __shared__ unsigned short tile[64][65];   // [r][c], pad 1 (2-way banks = free)
  const int e = blockIdx.z;
  in  += (size_t)e * R * C;
  out += (size_t)e * C * R;
  const int c0 = blockIdx.x * 64, r0 = blockIdx.y * 64;
  const int tid = threadIdx.x;
  const int rL = tid >> 4;                  // 0..15
  const int cq = (tid & 15) * 4;            // col quad
#pragma unroll
  for (int p = 0; p < 4; ++p) {
    const int r = rL + p * 16;
    float4 v = *(const float4*)&in[(size_t)(r0 + r) * C + c0 + cq];
    tile[r][cq + 0] = f2bf(v.x);
    tile[r][cq + 1] = f2bf(v.y);
    tile[r][cq + 2] = f2bf(v.z);
    tile[r][cq + 3] = f2bf(v.w);
  }
  __syncthreads();
  const int cL = tid >> 4;                  // 0..15
  const int rq = (tid & 15) * 4;            // row quad (consecutive lanes -> coalesced)
#pragma unroll
  for (int p = 0; p < 4; ++p) {
    const int cc = cL + p * 16;
    ushort4 o;
    o.x = tile[rq + 0][cc]; o.y = tile[rq + 1][cc];
    o.z = tile[rq + 2][cc]; o.w = tile[rq + 3][cc];
    *(ushort4*)&out[(size_t)(c0 + cc) * R + r0 + rq] = o;
  }
}

// ---------------- 4. Gather tokens per expert into contiguous bf16 rows ----------------
__global__ __launch_bounds__(64)
void moe_gather(const float* __restrict__ x, const int* __restrict__ elist,
                const int* __restrict__ counts, unsigned short* __restrict__ Xg)
{
  const int p = blockIdx.x, e = blockIdx.y;
  const int lane = threadIdx.x;
  unsigned short* dst = Xg + ((size_t)e * CAP + p) * DMODEL;
  if (p >= counts[e]) {
    ushort4 z; z.x = z.y = z.z = z.w = 0;
#pragma unroll
    for (int j = 0; j < 3; ++j) ((ushort4*)dst)[j * 64 + lane] = z;
    return;
  }
  const int tok = elist[e * CAP + p];
  const float4* src = (const float4*)(x + (size_t)tok * DMODEL);
#pragma unroll
  for (int j = 0; j < 3; ++j) {
    float4 v = src[j * 64 + lane];
    ushort4 o;
    o.x = f2bf(v.x); o.y = f2bf(v.y); o.z = f2bf(v.z); o.w = f2bf(v.w);
    ((ushort4*)dst)[j * 64 + lane] = o;
  }
}

// ---------------- 5. Grouped GEMM: reg-staged, XOR-swizzled row-major LDS ----------------
// VERBATIM r11 structure (verified: 77us/GEMM, VGPR 76, no spill, clean WRITE).
// r12 lesson: converting the LOADT/STORET macros to lambdas broke SROA -- the
// captured float4 arrays became memory-homed (scratch), VGPR 76->64, WRITE
// 73.7MB->880MB, 77us->360us. Macros with named scalars ONLY.
// 128x128 tile, 256 thr = 4 waves (2x2), wave out 64x64, acc[4][4] (-> AGPRs).
// Bare __launch_bounds__(256): a min-waves floor caps arch VGPRs at 64 (r9).
// Transport: global_load_dwordx4 -> regs -> ds_write_b128; loads for tile t+1
// issue BEFORE compute(t). LDS [128][64] ush, 16B-chunk XOR swizzle both sides.
// ORD=0: mt fastest (GEMM1); ORD=1: nt fastest (GEMM2, fetch fix, r11).
// EPI=0: bf16(fast_gelu(acc+bias)) via LDS-staged coalesced stores.
// EPI=1: direct f32, bias folded into combine; ks picks Cout0/1.
template <int EPI, int ORD>
__global__ __launch_bounds__(256)
void moe_rs(const unsigned short* __restrict__ Ag, int lda,
            const unsigned short* __restrict__ Bg, int ldb,
            void* __restrict__ Cout0, void* __restrict__ Cout1, int ldc,
            const float* __restrict__ bias,
            int Nsize, int NT, int MT, int NTN)
{
  __shared__ __align__(16) unsigned short lds[2 * 8192];   // A | B, 32 KiB
  unsigned short* const ldsA = lds;
  unsigned short* const ldsB = lds + 8192;

  // XCD swizzle: per-XCD contiguous chunk = one expert's tiles
  const int cpx = gridDim.x >> 3;
  const int swz = (blockIdx.x & 7) * cpx + (blockIdx.x >> 3);
  const int e  = swz / cpx;
  int rd = swz - e * cpx;
  int mt, nt, ks;
  if (ORD == 0) { mt = rd % MT;  rd /= MT;  nt = rd % NTN; ks = rd / NTN; }
  else          { nt = rd % NTN; rd /= NTN; mt = rd % MT;  ks = rd / MT;  }
  const int m0 = mt * 128, n0 = nt * 128;
  const int kb = ks * NT * 64;

  const unsigned short* Ae = Ag + (size_t)e * CAP * lda;
  const unsigned short* Be = Bg + (size_t)e * Nsize * ldb;

  const int tid = threadIdx.x, lane = tid & 63, wid = tid >> 6;
  const int wr = wid >> 1, wc = wid & 1;
  const int r16 = lane & 15, g4 = lane >> 4;

  // staging: rows srow+{0,32,64,96}, 16B chunk scol; global row-contiguous
  // (8 lanes x 16B = 128B per row), LDS dest chunk XOR-swizzled.
  const int srow  = tid >> 3;                 // 0..31
  const int scol  = tid & 7;                  // 0..7
  const int scolX = scol ^ (srow & 7);        // (srow+32k)&7 == srow&7
  const unsigned short* pA = Ae + (size_t)(m0 + srow) * lda + scol * 8 + kb;
  const unsigned short* pB = Be + (size_t)(n0 + srow) * ldb + scol * 8 + kb;
  unsigned short* qA = &ldsA[srow * 64 + scolX * 8];
  unsigned short* qB = &ldsB[srow * 64 + scolX * 8];

  float4 a0, a1, a2, a3, b0, b1, b2, b3;

#define LOADT(tt) do {                                                        \
    const size_t ko = (size_t)(tt) * 64;                                      \
    a0 = *(const float4*)(pA + ko);                                           \
    a1 = *(const float4*)(pA + ko + (size_t)32 * lda);                        \
    a2 = *(const float4*)(pA + ko + (size_t)64 * lda);                        \
    a3 = *(const float4*)(pA + ko + (size_t)96 * lda);                        \
    b0 = *(const float4*)(pB + ko);                                           \
    b1 = *(const float4*)(pB + ko + (size_t)32 * ldb);                        \
    b2 = *(const float4*)(pB + ko + (size_t)64 * ldb);                        \
    b3 = *(const float4*)(pB + ko + (size_t)96 * ldb);                        \
  } while (0)

#define STORET() do {                                                         \
    *(float4*)(qA)        = a0;  *(float4*)(qA + 2048) = a1;                  \
    *(float4*)(qA + 4096) = a2;  *(float4*)(qA + 6144) = a3;                  \
    *(float4*)(qB)        = b0;  *(float4*)(qB + 2048) = b1;                  \
    *(float4*)(qB + 4096) = b2;  *(float4*)(qB + 6144) = b3;                  \
  } while (0)

  f32x4 acc[4][4];
#pragma unroll
  for (int i = 0; i < 4; ++i)
#pragma unroll
    for (int j = 0; j < 4; ++j) acc[i][j] = (f32x4){0.f, 0.f, 0.f, 0.f};

  // per-thread read offsets (swizzled): chunk = (kh*4+g4) ^ (row&7)
  const int cx0 = (g4 ^ (r16 & 7)) * 8;
  const int rA = (wr * 64 + r16) * 64;    // + mi*16*64
  const int rB = (wc * 64 + r16) * 64;

  LOADT(0);
  for (int t = 0; t < NT; ++t) {
    __syncthreads();                 // all waves done reading LDS(t-1)
    STORET();                        // compiler inserts vmcnt wait here
    if (t + 1 < NT) LOADT(t + 1);    // in flight during compute(t)
    __syncthreads();                 // LDS(t) visible
#pragma unroll
    for (int kh = 0; kh < 2; ++kh) {
      const int cx = cx0 ^ (kh * 32);
      bf16x8 aF[4], bF[4];
#pragma unroll
      for (int mi = 0; mi < 4; ++mi)
        aF[mi] = *(const bf16x8*)&ldsA[rA + mi * 1024 + cx];
#pragma unroll
      for (int ni = 0; ni < 4; ++ni)
        bF[ni] = *(const bf16x8*)&ldsB[rB + ni * 1024 + cx];
#pragma unroll
      for (int mi = 0; mi < 4; ++mi)
#pragma unroll
        for (int ni = 0; ni < 4; ++ni)
          acc[mi][ni] = __builtin_amdgcn_mfma_f32_16x16x32_bf16(aF[mi], bF[ni], acc[mi][ni], 0, 0, 0);
    }
  }
#undef LOADT
#undef STORET

  // ---- epilogue. C/D layout: col = lane&15, row = 4*(lane>>4)+reg ----
  const float* bvec = bias + (size_t)e * Nsize;
  if constexpr (EPI == 0) {
    // stage bf16 tile in LDS ([128][128] ushort = exactly 32KB), coalesced out
    __syncthreads();
#pragma unroll
    for (int ni = 0; ni < 4; ++ni) {
      const int lc = wc * 64 + ni * 16 + r16;
      const float bv = bvec[n0 + lc];
#pragma unroll
      for (int mi = 0; mi < 4; ++mi) {
        const int lr0 = wr * 64 + mi * 16 + 4 * g4;
#pragma unroll
        for (int reg = 0; reg < 4; ++reg) {
          lds[(lr0 + reg) * 128 + lc] = f2bf(fast_gelu(acc[mi][ni][reg] + bv));
        }
      }
    }
    __syncthreads();
    unsigned short* C = (unsigned short*)Cout0 + (size_t)e * CAP * ldc;
#pragma unroll
    for (int it = 0; it < 8; ++it) {               // 2048 chunks of 8 shorts
      const int chunk = it * 256 + tid;
      const int row = chunk >> 4, c8 = chunk & 15;
      *(float4*)(C + (size_t)(m0 + row) * ldc + n0 + c8 * 8) = *(const float4*)&lds[chunk * 8];
    }
  } else {
    float* C = (float*)(ks ? Cout1 : Cout0) + (size_t)e * CAP * ldc;
#pragma unroll
    for (int ni = 0; ni < 4; ++ni) {
      const int gc = n0 + wc * 64 + ni * 16 + r16;
#pragma unroll
      for (int mi = 0; mi < 4; ++mi) {
        const int gr0 = m0 + wr * 64 + mi * 16 + 4 * g4;
#pragma unroll
        for (int reg = 0; reg < 4; ++reg)
          C[(size_t)(gr0 + reg) * ldc + gc] = acc[mi][ni][reg];
      }
    }
  }
}

// ---------------- 6. Combine: out[t] = sum over kept slots w*(Y0+Y1+b2[e]) ----------------
__global__ __launch_bounds__(192)
void moe_combine(const float* __restrict__ Y0, const float* __restrict__ Y1,
                 const float* __restrict__ b2, const int* __restrict__ eidx,
                 const float* __restrict__ pw, const int* __restrict__ slotpos,
                 float* __restrict__ out)
{
  const int t = blockIdx.x;
  const int tid = threadIdx.x;
  float4 acc; acc.x = acc.y = acc.z = acc.w = 0.f;
#pragma unroll
  for (int s = 0; s < 2; ++s) {
    const int pos = slotpos[t * 2 + s];
    if (pos >= 0) {
      const int e = eidx[t * 2 + s];
      const float w = pw[t * 2 + s];
      const size_t ro = ((size_t)e * CAP + pos) * DMODEL;
      float4 y0 = ((const float4*)(Y0 + ro))[tid];
      float4 y1 = ((const float4*)(Y1 + ro))[tid];
      float4 bv = ((const float4*)(b2 + (size_t)e * DMODEL))[tid];
      acc.x += w * (y0.x + y1.x + bv.x);
      acc.y += w * (y0.y + y1.y + bv.y);
      acc.z += w * (y0.z + y1.z + bv.z);
      acc.w += w * (y0.w + y1.w + bv.w);
    }
  }
  ((float4*)out)[(size_t)t * (DMODEL / 4) + tid] = acc;
}

// ---------------- launch ----------------
extern "C" void kernel_launch(void* const* d_in, const int* in_sizes, int n_in,
                              void* d_out, int out_size, void* d_ws, size_t ws_size,
                              hipStream_t stream)
{
  const float* x  = (const float*)d_in[0];
  const float* Wr = (const float*)d_in[1];
  const float* w1 = (const float*)d_in[2];
  const float* b1 = (const float*)d_in[3];
  const float* w2 = (const float*)d_in[4];
  const float* b2 = (const float*)d_in[5];
  float* out = (float*)d_out;

  char* ws = (char*)d_ws;
  const size_t SZ_W1T = (size_t)NEXP * HDIM * DMODEL * 2;   // 37.75 MB
  const size_t SZ_W2T = (size_t)NEXP * DMODEL * HDIM * 2;   // 37.75 MB
  const size_t SZ_XG  = (size_t)NEXP * CAP * DMODEL * 2;    // 18.87 MB
  const size_t SZ_H   = (size_t)NEXP * CAP * HDIM * 2;      // 75.50 MB
  const size_t SZ_Y   = (size_t)NEXP * CAP * DMODEL * 4;    // 37.75 MB
  unsigned short* w1t = (unsigned short*)(ws);               size_t off = SZ_W1T;
  unsigned short* w2t = (unsigned short*)(ws + off);         off += SZ_W2T;
  unsigned short* Xg  = (unsigned short*)(ws + off);         off += SZ_XG;
  unsigned short* Hb  = (unsigned short*)(ws + off);         off += SZ_H;
  float*          Y0  = (float*)(ws + off);                  off += SZ_Y;
  int*   eidx    = (int*)(ws + off);                         off += (size_t)TOK * 2 * 4;
  float* pw      = (float*)(ws + off);                       off += (size_t)TOK * 2 * 4;
  int*   slotpos = (int*)(ws + off);                         off += (size_t)NFLAT * 4;
  int*   elist   = (int*)(ws + off);                         off += (size_t)NEXP * CAP * 4;
  int*   counts  = (int*)(ws + off);
  float* Y1 = (float*)w1t;   // alias: w1t dead after GEMM1; sizes match exactly

  // 1. router (fp64 logits -> exact top-2 ordering)
  moe_router<<<TOK / 4, 256, 0, stream>>>(x, Wr, eidx, pw);
  // 2. capacity assignment
  moe_assign<<<NEXP, 256, 0, stream>>>(eidx, slotpos, elist, counts);
  // 3. weight transposes (n-major bf16, vectorized)
  transpose_bf16<<<dim3(HDIM / 64, DMODEL / 64, NEXP), 256, 0, stream>>>(w1, w1t, DMODEL, HDIM);
  transpose_bf16<<<dim3(DMODEL / 64, HDIM / 64, NEXP), 256, 0, stream>>>(w2, w2t, HDIM, DMODEL);
  // 4. gather per-expert token rows (bf16), zero pad rows
  moe_gather<<<dim3(CAP, NEXP), 64, 0, stream>>>(x, elist, counts, Xg);
  // 5. grouped GEMMs (reg-staged pipeline, 128x128 — r11-verified config)
  //    GEMM1: [1536x3072x768]/expert -> 12*24*8 = 2304 blocks, NT=12, mt-fastest
  moe_rs<0, 0><<<2304, 256, 0, stream>>>(
      Xg, DMODEL, w1t, DMODEL, Hb, Hb, HDIM, b1, HDIM, /*NT=*/12, /*MT=*/12, /*NTN=*/24);
  //    GEMM2: [1536x768x3072]/expert, K-split x2 -> 1152 blocks, NT=24, nt-fastest
  moe_rs<1, 1><<<1152, 256, 0, stream>>>(
      Hb, HDIM, w2t, HDIM, Y0, Y1, DMODEL, b2, DMODEL, /*NT=*/24, /*MT=*/12, /*NTN=*/6);
  // 6. weighted combine (adds K-split partials + bias; deterministic)
  moe_combine<<<TOK, 192, 0, stream>>>(Y0, Y1, b2, eidx, pw, slotpos, out);
}